// Round 3
// baseline (491.940 us; speedup 1.0000x reference)
//
#include <hip/hip_runtime.h>
#include <cstddef>

// Problem shape (fixed): N=50000, K=16, C_IN=128, C2=256, C_OUT=128.
#define C_IN  128
#define C2    256
#define C_OUT 128
#define KNBR  16
#define PTS   32     // points per gather_out block

typedef unsigned short u16;
typedef __attribute__((ext_vector_type(8))) short bf16x8;   // 8 bf16 (4 VGPRs)
typedef __attribute__((ext_vector_type(8))) unsigned short u16x8; // 16B payload
typedef __attribute__((ext_vector_type(4))) float f32x4;

__device__ __forceinline__ float bf2f(u16 h) {
    return __uint_as_float(((unsigned int)h) << 16);
}
__device__ __forceinline__ u16 f2bf(float x) {
    unsigned int u = __float_as_uint(x);
    return (u16)((u + 0x7fffu + ((u >> 16) & 1u)) >> 16);
}

// Transpose + convert weights to bf16, n-major [N][K].
__global__ void prep_k(const float* __restrict__ W1, const float* __restrict__ Ws,
                       const float* __restrict__ Wm, u16* __restrict__ W1t,
                       u16* __restrict__ Wst, u16* __restrict__ Wmt)
{
    const int n = blockIdx.x, t = threadIdx.x;
    if (blockIdx.y == 0) {
        if (t < 128) W1t[n * 128 + t] = f2bf(W1[t * 256 + n]);
    } else if (blockIdx.y == 1) {
        Wst[n * 256 + t] = f2bf(Ws[t * 256 + n]);
    } else {
        if (n < 128) Wmt[n * 256 + t] = f2bf(Wm[t * 128 + n]);
    }
}

// ---------------------------------------------------------------------------
// LESSONS ENCODED:
//  R7:  accumulator arrays indexed by non-unrolled loop vars spill to scratch.
//  R9:  scattered sub-dword global stores -> write-allocate RMW (16x bytes).
//  R10: 1-block/CU weight-stationary waves have zero latency hiding.
//  R11: packed row CHANNEL-INTERLEAVED [ey0,x0,ey1,x1,...]: one dwordx4/lane
//       per neighbor row; e,x same lane for the FMA.
//  R12: gather is pinned at ~3.6 TB/s on the L2-miss path (random rows, no
//       locality to recover, bf16 = precision floor) -> delete work, don't
//       polish access patterns. FETCH stays ~370 MB regardless.
//  R13 (this round): weights (W1t+Wst+Wmt = 256 KB) are L2-resident; staging
//       them through LDS every K-step cost 26 barriers/block in mlp_k and
//       held it at ~100 TF effective (~110 us vs ~35 roofline). Read MFMA
//       B-fragments DIRECTLY from global (16 rows x 64B aligned segments,
//       always L2-hit). mlp_k: LDS 69.6->50 KB (3 blocks/CU), 5 barriers.
//       gather_out_k: LDS 37.4->18.9 KB (6 blocks/CU) so the GEMM phase no
//       longer starves the gather phase's occupancy (R2 regression).
// packed row (512 u16): 256 pairs of (ey[c], x[c]), both bf16.
// ---------------------------------------------------------------------------

// Fused MLP, 64-row blocks (50 KB LDS -> 3 blocks/CU):
//   x  = BN(relu(F @ W1 + b1))  -> xs (LDS)
//   ey = exp(x @ Ws)            -> As reuse -> combined interleaved flush
// B-fragments read directly from L2-resident W1t/Wst; only 5 barriers total.
__global__ __launch_bounds__(256, 3)
void mlp_k(const float* __restrict__ F, const u16* __restrict__ W1t,
           const u16* __restrict__ Wst,
           const float* __restrict__ bias, const float* __restrict__ gamma,
           const float* __restrict__ beta, const float* __restrict__ mean,
           const float* __restrict__ var,
           u16* __restrict__ packed, int N)
{
    __shared__ u16 As[64][136];    // features tile (GEMM1 A); ey staging (epi 2)
    __shared__ u16 xs[64][264];    // x tile, full K=256

    const int tid = threadIdx.x;
    const int w = tid >> 6, l = tid & 63, q = l >> 4, r = l & 15;
    const int wm = w & 1, wn = w >> 1;
    const int m0 = blockIdx.x * 64;

    // stage As: 64 x 128 fp32 -> bf16 (2048 float4, 8/thread)
    #pragma unroll
    for (int i = 0; i < 8; i++) {
        int idx = tid + i * 256;
        int row = idx >> 5, c4 = (idx & 31) * 4;
        int gm = m0 + row;
        float4 v = make_float4(0.f, 0.f, 0.f, 0.f);
        if (gm < N) v = *(const float4*)(F + (size_t)gm * C_IN + c4);
        ushort4 h;
        h.x = f2bf(v.x); h.y = f2bf(v.y); h.z = f2bf(v.z); h.w = f2bf(v.w);
        *(ushort4*)&As[row][c4] = h;
    }
    __syncthreads();   // As ready

    // ---- GEMM1: x = F @ W1, two 128-col halves; B direct from L2 ----
    #pragma unroll
    for (int nh = 0; nh < 2; nh++) {
        f32x4 acc[2][4] = {};
        #pragma unroll
        for (int k0 = 0; k0 < C_IN; k0 += 64) {
            #pragma unroll
            for (int h = 0; h < 2; h++) {
                bf16x8 af[2], bfr[4];
                #pragma unroll
                for (int i = 0; i < 2; i++)
                    af[i] = *(const bf16x8*)&As[wm * 32 + i * 16 + r][k0 + h * 32 + q * 8];
                #pragma unroll
                for (int j = 0; j < 4; j++)
                    bfr[j] = *(const bf16x8*)(W1t +
                        (size_t)(nh * 128 + wn * 64 + j * 16 + r) * C_IN +
                        k0 + h * 32 + q * 8);
                #pragma unroll
                for (int i = 0; i < 2; i++)
                    #pragma unroll
                    for (int j = 0; j < 4; j++)
                        acc[i][j] = __builtin_amdgcn_mfma_f32_16x16x32_bf16(
                            af[i], bfr[j], acc[i][j], 0, 0, 0);
            }
        }
        // epilogue 1: BN(relu(z+bias)) -> xs (LDS only)
        #pragma unroll
        for (int j = 0; j < 4; j++) {
            const int ch = nh * 128 + wn * 64 + j * 16 + r;
            const float bi = bias[ch], be = beta[ch], mu = mean[ch];
            const float iv = gamma[ch] * rsqrtf(var[ch] + 1e-5f);
            #pragma unroll
            for (int i = 0; i < 2; i++) {
                const int mb = wm * 32 + i * 16 + q * 4;
                #pragma unroll
                for (int p = 0; p < 4; p++) {
                    float x = fmaxf(acc[i][j][p] + bi, 0.f);
                    x = (x - mu) * iv + be;
                    xs[mb + p][ch] = f2bf(x);
                }
            }
        }
    }
    __syncthreads();   // xs complete; all As (GEMM1) reads done -> As reusable

    // ---- GEMM2: ey = exp(x @ Ws); B direct from L2; flush per half ----
    #pragma unroll
    for (int nh = 0; nh < 2; nh++) {
        f32x4 acc[2][4] = {};
        #pragma unroll
        for (int k0 = 0; k0 < C2; k0 += 64) {
            #pragma unroll
            for (int h = 0; h < 2; h++) {
                bf16x8 af[2], bfr[4];
                #pragma unroll
                for (int i = 0; i < 2; i++)
                    af[i] = *(const bf16x8*)&xs[wm * 32 + i * 16 + r][k0 + h * 32 + q * 8];
                #pragma unroll
                for (int j = 0; j < 4; j++)
                    bfr[j] = *(const bf16x8*)(Wst +
                        (size_t)(nh * 128 + wn * 64 + j * 16 + r) * C2 +
                        k0 + h * 32 + q * 8);
                #pragma unroll
                for (int i = 0; i < 2; i++)
                    #pragma unroll
                    for (int j = 0; j < 4; j++)
                        acc[i][j] = __builtin_amdgcn_mfma_f32_16x16x32_bf16(
                            af[i], bfr[j], acc[i][j], 0, 0, 0);
            }
        }
        if (nh == 1) __syncthreads();   // flush-half-0's As reads done everywhere
        // epilogue 2: ey -> As reuse (cols local to this nh-half)
        #pragma unroll
        for (int j = 0; j < 4; j++) {
            const int chl = wn * 64 + j * 16 + r;   // 0..127 within half
            #pragma unroll
            for (int i = 0; i < 2; i++) {
                const int mb = wm * 32 + i * 16 + q * 4;
                #pragma unroll
                for (int p = 0; p < 4; p++)
                    As[mb + p][chl] = f2bf(__expf(acc[i][j][p]));
            }
        }
        __syncthreads();       // As (ey half) complete
        // combined interleaved flush for this half:
        // 64 rows x 128 pairs -> 64 x 512 B (2048 uint4, 8/thread).
        #pragma unroll
        for (int i = 0; i < 8; i++) {
            int idx = tid + i * 256;
            int row = idx >> 5, slot = idx & 31;   // slot: uint4 within row-half
            int c0 = slot * 4;                     // first local channel of 4
            if (m0 + row < N) {
                ushort4 e  = *(const ushort4*)&As[row][c0];
                ushort4 xv = *(const ushort4*)&xs[row][nh * 128 + c0];
                uint4 qv;
                qv.x = (unsigned)e.x | ((unsigned)xv.x << 16);
                qv.y = (unsigned)e.y | ((unsigned)xv.y << 16);
                qv.z = (unsigned)e.z | ((unsigned)xv.z << 16);
                qv.w = (unsigned)e.w | ((unsigned)xv.w << 16);
                *(uint4*)(packed + (size_t)(m0 + row) * 512 + nh * 256 + slot * 8) = qv;
            }
        }
    }
}

// Fused gather + attentive pool + output GEMM. 32 points/block, 4 waves.
// Phase 1: each wave pools 8 points (16 x 1KB random rows each) -> feat LDS
//          tile [32][264] bf16 (lane l owns channels 4l..4l+3).
// Phase 2: out[32 x 128] = feat @ Wmt + bm via MFMA, K=256 in 4 k-steps,
//          B-fragments DIRECT from L2-resident Wmt (no Bs, no k-loop barriers);
//          fp32 epilogue staging ALIASES the feat buffer.
// LDS: 2KB rows + 16.9KB feat/STF = 18.9KB -> 6 blocks/CU (24 waves).
__global__ __launch_bounds__(256, 6)
void gather_out_k(const u16* __restrict__ packed, const int* __restrict__ nidx,
                  const u16* __restrict__ Bt, const float* __restrict__ bias,
                  float* __restrict__ Cf, int N)
{
    __shared__ int rows[PTS * KNBR];                 // 2 KB
    __shared__ __align__(16) u16 fsm[PTS * 264];     // feat bf16 / STF fp32 alias

    const int tid = threadIdx.x;
    const int w = tid >> 6, l = tid & 63, q = l >> 4, r = l & 15;
    const int m0 = blockIdx.x * PTS;

    // stage neighbor indices: PTS*16 = 512 ints, 2/thread
    #pragma unroll
    for (int i = 0; i < 2; i++) {
        int idx = tid + i * 256;
        int n = m0 + (idx >> 4);
        rows[idx] = (n < N) ? nidx[n * KNBR + (idx & 15)] : 0;
    }
    __syncthreads();

    // ---- phase 1: gather + pool, wave w -> points w*8 .. w*8+7 ----
    #pragma unroll 1
    for (int ip = 0; ip < 8; ip++) {
        const int pl = w * 8 + ip;
        u16x8 v[KNBR];
        #pragma unroll
        for (int k = 0; k < KNBR; k++)
            v[k] = *(const u16x8*)(packed + (size_t)rows[pl * KNBR + k] * 512 + l * 8);
        float num[4] = {0.f, 0.f, 0.f, 0.f};
        float den[4] = {0.f, 0.f, 0.f, 0.f};
        #pragma unroll
        for (int k = 0; k < KNBR; k++) {
            #pragma unroll
            for (int c = 0; c < 4; c++) {
                float e = bf2f((u16)v[k][2 * c]);
                float x = bf2f((u16)v[k][2 * c + 1]);
                den[c] += e;
                num[c] = fmaf(e, x, num[c]);
            }
        }
        ushort4 o;
        o.x = f2bf(num[0] / den[0]); o.y = f2bf(num[1] / den[1]);
        o.z = f2bf(num[2] / den[2]); o.w = f2bf(num[3] / den[3]);
        *(ushort4*)&fsm[pl * 264 + l * 4] = o;   // rows >= N: garbage, never stored
    }
    __syncthreads();   // feat tile complete

    // ---- phase 2: out GEMM, wave grid 2M x 2N; B direct from L2 ----
    const int wm = w & 1, wn = w >> 1;
    f32x4 acc[4] = {};

    #pragma unroll
    for (int k0 = 0; k0 < C2; k0 += 64) {
        #pragma unroll
        for (int h = 0; h < 2; h++) {
            bf16x8 af, bfr[4];
            af = *(const bf16x8*)&fsm[(wm * 16 + r) * 264 + k0 + h * 32 + q * 8];
            #pragma unroll
            for (int j = 0; j < 4; j++)
                bfr[j] = *(const bf16x8*)(Bt +
                    (size_t)(wn * 64 + j * 16 + r) * C2 + k0 + h * 32 + q * 8);
            #pragma unroll
            for (int j = 0; j < 4; j++)
                acc[j] = __builtin_amdgcn_mfma_f32_16x16x32_bf16(
                    af, bfr[j], acc[j], 0, 0, 0);
        }
    }
    __syncthreads();   // all feat reads done -> safe to alias STF onto fsm

    // epilogue: stage fp32 tile in aliased LDS, then full-line float4 flush
    float* STF = (float*)fsm;              // [32][132]
    #pragma unroll
    for (int j = 0; j < 4; j++) {
        const int ch = wn * 64 + j * 16 + r;
        const float bo = bias[ch];
        const int mb = wm * 16 + q * 4;
        #pragma unroll
        for (int p = 0; p < 4; p++)
            STF[(mb + p) * 132 + ch] = acc[j][p] + bo;
    }
    __syncthreads();
    #pragma unroll
    for (int i = 0; i < 4; i++) {          // 32x128 fp32 = 1024 float4
        int idx = tid + i * 256;
        int row = idx >> 5, c4 = (idx & 31) * 4;
        if (m0 + row < N)
            *(float4*)(Cf + (size_t)(m0 + row) * C_OUT + c4) =
                *(const float4*)&STF[row * 132 + c4];
    }
}

extern "C" void kernel_launch(void* const* d_in, const int* in_sizes, int n_in,
                              void* d_out, int out_size, void* d_ws, size_t ws_size,
                              hipStream_t stream)
{
    const float* features = (const float*)d_in[0];
    const int*   nidx     = (const int*)d_in[1];
    const float* W1       = (const float*)d_in[2];
    const float* b1       = (const float*)d_in[3];
    const float* gamma    = (const float*)d_in[4];
    const float* beta     = (const float*)d_in[5];
    const float* mean     = (const float*)d_in[6];
    const float* var      = (const float*)d_in[7];
    const float* Ws       = (const float*)d_in[8];
    const float* Wm       = (const float*)d_in[9];
    const float* bm       = (const float*)d_in[10];
    float* out = (float*)d_out;

    const int N = in_sizes[0] / C_IN;   // 50000

    u16* packed = (u16*)d_ws;                      // N x 512 interleaved pairs
    u16* W1t    = packed + (size_t)N * 512;        // 256 x 128
    u16* Wst    = W1t + 256 * 128;                 // 256 x 256
    u16* Wmt    = Wst + 256 * 256;                 // 128 x 256

    prep_k<<<dim3(256, 3), 256, 0, stream>>>(W1, Ws, Wm, W1t, Wst, Wmt);

    const int MT = (N + 63) / 64;        // 782
    const int GT = (N + PTS - 1) / PTS;  // 1563

    mlp_k<<<MT, 256, 0, stream>>>(features, W1t, Wst, b1, gamma, beta,
                                  mean, var, packed, N);
    gather_out_k<<<GT, 256, 0, stream>>>(packed, nidx, Wmt, bm, out, N);
}

// Round 4
// 304.477 us; speedup vs baseline: 1.6157x; 1.6157x over previous
//
#include <hip/hip_runtime.h>
#include <cstddef>

// Problem shape (fixed): N=50000, K=16, C_IN=128, C2=256, C_OUT=128.
#define C_IN  128
#define C2    256
#define C_OUT 128
#define KNBR  16
#define PTS   32     // points per gather_out block

typedef unsigned short u16;
typedef __attribute__((ext_vector_type(8))) short bf16x8;   // 8 bf16 (4 VGPRs)
typedef __attribute__((ext_vector_type(8))) unsigned short u16x8; // 16B payload
typedef __attribute__((ext_vector_type(4))) float f32x4;

__device__ __forceinline__ float bf2f(u16 h) {
    return __uint_as_float(((unsigned int)h) << 16);
}
__device__ __forceinline__ u16 f2bf(float x) {
    unsigned int u = __float_as_uint(x);
    return (u16)((u + 0x7fffu + ((u >> 16) & 1u)) >> 16);
}

// Transpose + convert weights to bf16, n-major [N][K]; fold BN params.
__global__ void prep_k(const float* __restrict__ W1, const float* __restrict__ Ws,
                       const float* __restrict__ Wm, const float* __restrict__ b1,
                       const float* __restrict__ gamma, const float* __restrict__ beta,
                       const float* __restrict__ mean, const float* __restrict__ var,
                       u16* __restrict__ W1t, u16* __restrict__ Wst,
                       u16* __restrict__ Wmt, float4* __restrict__ bnp)
{
    const int n = blockIdx.x, t = threadIdx.x;
    if (blockIdx.y == 0) {
        if (t < 128) W1t[n * 128 + t] = f2bf(W1[t * 256 + n]);
    } else if (blockIdx.y == 1) {
        Wst[n * 256 + t] = f2bf(Ws[t * 256 + n]);
    } else if (blockIdx.y == 2) {
        if (n < 128) Wmt[n * 256 + t] = f2bf(Wm[t * 128 + n]);
    } else if (n == 0) {
        // x = (relu(z+b1)-mu)*iv + be = relu(z+c1)*c2 + c3
        float iv = gamma[t] * rsqrtf(var[t] + 1e-5f);
        bnp[t] = make_float4(b1[t], iv, beta[t] - mean[t] * iv, 0.f);
    }
}

// ---------------------------------------------------------------------------
// LESSONS ENCODED:
//  R7:  accumulator arrays indexed by non-unrolled loop vars spill to scratch.
//  R9:  scattered sub-dword global stores -> write-allocate RMW (16x bytes).
//  R10: 1-block/CU weight-stationary waves have zero latency hiding.
//  R11: packed row CHANNEL-INTERLEAVED [ey0,x0,ey1,x1,...]: one dwordx4/lane
//       per neighbor row; e,x same lane for the FMA.
//  R12: gather random-read fabric pins at ~3.6-4.0 TB/s; FETCH ~370 MB is
//       structural (uniform-random indices). Delete work, don't polish.
//  R13: weights (256 KB) are L2-resident -> MFMA B-fragments direct from
//       global; no LDS staging, no k-loop barriers.
//  R14 (this round): launch_bounds cap BELOW the staging payload => compiler
//       spills the whole gather array to scratch (WRITE 25->667 MB, 2x dur).
//       Cap must exceed payload+state with headroom: v[8] two-pass @ (256,5).
//       mlp_k rewritten WAVE-PRIVATE (16 rows/wave): zero barriers; ey and x
//       share the SAME acc layout -> interleaved (ey|x<<16) dword store is
//       lane-local, no flush staging; x-transpose bounces through 8.4 KB
//       per-wave LDS guarded by a wave-local lgkmcnt(0).
// packed row (512 u16): 256 pairs of (ey[c], x[c]), both bf16.
// ---------------------------------------------------------------------------

// Wave-private fused MLP: each wave owns 16 rows end-to-end.
//   GEMM1: x = BN(relu(F@W1+b1))   (K=128, 16 col-tiles, 64 MFMA)
//   GEMM2: ey = exp(x@Ws)          (K=256, 16 col-tiles, 128 MFMA)
// LDS: xw[4][16][264] = 33.8 KB. No __syncthreads anywhere.
__global__ __launch_bounds__(256, 3)
void mlp_k(const float* __restrict__ F, const u16* __restrict__ W1t,
           const u16* __restrict__ Wst, const float4* __restrict__ bnp,
           u16* __restrict__ packed, int N)
{
    __shared__ u16 xw[4][16][264];   // per-wave x tile (bf16), transpose bounce

    const int tid = threadIdx.x;
    const int w = tid >> 6, l = tid & 63, q = l >> 4, r = l & 15;
    const int m0 = blockIdx.x * 64 + w * 16;   // this wave's first row

    // ---- A-fragments from F: rows m0+r, 4 k-tiles of 32 ----
    bf16x8 af[4];
    const int gr = m0 + r;
    #pragma unroll
    for (int t = 0; t < 4; t++) {
        float4 v0 = make_float4(0.f, 0.f, 0.f, 0.f), v1 = v0;
        if (gr < N) {
            const float* s = F + (size_t)gr * C_IN + t * 32 + q * 8;
            v0 = *(const float4*)s;
            v1 = *(const float4*)(s + 4);
        }
        bf16x8 a;
        a[0] = (short)f2bf(v0.x); a[1] = (short)f2bf(v0.y);
        a[2] = (short)f2bf(v0.z); a[3] = (short)f2bf(v0.w);
        a[4] = (short)f2bf(v1.x); a[5] = (short)f2bf(v1.y);
        a[6] = (short)f2bf(v1.z); a[7] = (short)f2bf(v1.w);
        af[t] = a;
    }

    // ---- GEMM1 + BN/ReLU -> xw (acc: col=r via j, row=q*4+p) ----
    {
        f32x4 acc[16];
        #pragma unroll
        for (int j = 0; j < 16; j++) acc[j] = (f32x4){0.f, 0.f, 0.f, 0.f};
        #pragma unroll
        for (int j = 0; j < 16; j++) {
            #pragma unroll
            for (int t = 0; t < 4; t++) {
                bf16x8 bf = *(const bf16x8*)(
                    W1t + (size_t)(j * 16 + r) * C_IN + t * 32 + q * 8);
                acc[j] = __builtin_amdgcn_mfma_f32_16x16x32_bf16(
                    af[t], bf, acc[j], 0, 0, 0);
            }
        }
        #pragma unroll
        for (int j = 0; j < 16; j++) {
            const float4 bp = bnp[j * 16 + r];
            #pragma unroll
            for (int p = 0; p < 4; p++) {
                float x = fmaxf(acc[j][p] + bp.x, 0.f) * bp.y + bp.z;
                xw[w][q * 4 + p][j * 16 + r] = f2bf(x);
            }
        }
    }
    // wave-local: all this wave's LDS writes complete before cross-lane reads
    asm volatile("s_waitcnt lgkmcnt(0)" ::: "memory");

    // ---- GEMM2: A = x (re-read transposed), B = Wst direct from L2 ----
    bf16x8 xa[8];
    #pragma unroll
    for (int t = 0; t < 8; t++)
        xa[t] = *(const bf16x8*)&xw[w][r][t * 32 + q * 8];

    f32x4 acc2[16];
    #pragma unroll
    for (int j = 0; j < 16; j++) acc2[j] = (f32x4){0.f, 0.f, 0.f, 0.f};
    #pragma unroll
    for (int j = 0; j < 16; j++) {
        #pragma unroll
        for (int t = 0; t < 8; t++) {
            bf16x8 bf = *(const bf16x8*)(
                Wst + (size_t)(j * 16 + r) * C2 + t * 32 + q * 8);
            acc2[j] = __builtin_amdgcn_mfma_f32_16x16x32_bf16(
                xa[t], bf, acc2[j], 0, 0, 0);
        }
    }

    // ---- epilogue: ey=exp(acc2); pair with x (same layout, lane-local) ----
    // store u32 (ey | x<<16) at packed[gm*512 + ch*2]; 16 lanes cover 64B.
    #pragma unroll
    for (int j = 0; j < 16; j++) {
        #pragma unroll
        for (int p = 0; p < 4; p++) {
            const int gm = m0 + q * 4 + p;
            if (gm < N) {
                unsigned ey = f2bf(__expf(acc2[j][p]));
                unsigned xv = xw[w][q * 4 + p][j * 16 + r];  // own lane's write
                *(unsigned*)(packed + (size_t)gm * 512 + (j * 16 + r) * 2) =
                    ey | (xv << 16);
            }
        }
    }
}

// Fused gather + attentive pool + output GEMM. 32 points/block, 4 waves.
// Phase 1: each wave pools 8 points; 16 rows gathered in TWO passes of 8
//          (32-VGPR payload, fits under the (256,5) cap -> no scratch).
// Phase 2: out[32 x 128] = feat @ Wmt + bm, B direct from L2-resident Wmt;
//          fp32 epilogue staging ALIASES the feat buffer.
// LDS: 2KB rows + 16.9KB feat/STF = 18.9KB; VGPR cap 102 -> 5 blocks/CU.
__global__ __launch_bounds__(256, 5)
void gather_out_k(const u16* __restrict__ packed, const int* __restrict__ nidx,
                  const u16* __restrict__ Bt, const float* __restrict__ bias,
                  float* __restrict__ Cf, int N)
{
    __shared__ int rows[PTS * KNBR];                 // 2 KB
    __shared__ __align__(16) u16 fsm[PTS * 264];     // feat bf16 / STF fp32 alias

    const int tid = threadIdx.x;
    const int w = tid >> 6, l = tid & 63, q = l >> 4, r = l & 15;
    const int m0 = blockIdx.x * PTS;

    // stage neighbor indices: PTS*16 = 512 ints, 2/thread
    #pragma unroll
    for (int i = 0; i < 2; i++) {
        int idx = tid + i * 256;
        int n = m0 + (idx >> 4);
        rows[idx] = (n < N) ? nidx[n * KNBR + (idx & 15)] : 0;
    }
    __syncthreads();

    // ---- phase 1: gather + pool, wave w -> points w*8 .. w*8+7 ----
    #pragma unroll 1
    for (int ip = 0; ip < 8; ip++) {
        const int pl = w * 8 + ip;
        float num[4] = {0.f, 0.f, 0.f, 0.f};
        float den[4] = {0.f, 0.f, 0.f, 0.f};
        #pragma unroll 1
        for (int hf = 0; hf < 2; hf++) {
            u16x8 v[8];
            #pragma unroll
            for (int k = 0; k < 8; k++)
                v[k] = *(const u16x8*)(packed +
                    (size_t)rows[pl * KNBR + hf * 8 + k] * 512 + l * 8);
            #pragma unroll
            for (int k = 0; k < 8; k++) {
                #pragma unroll
                for (int c = 0; c < 4; c++) {
                    float e = bf2f((u16)v[k][2 * c]);
                    float x = bf2f((u16)v[k][2 * c + 1]);
                    den[c] += e;
                    num[c] = fmaf(e, x, num[c]);
                }
            }
        }
        ushort4 o;
        o.x = f2bf(num[0] / den[0]); o.y = f2bf(num[1] / den[1]);
        o.z = f2bf(num[2] / den[2]); o.w = f2bf(num[3] / den[3]);
        *(ushort4*)&fsm[pl * 264 + l * 4] = o;   // rows >= N: garbage, never stored
    }
    __syncthreads();   // feat tile complete

    // ---- phase 2: out GEMM, wave grid 2M x 2N; B direct from L2 ----
    const int wm = w & 1, wn = w >> 1;
    f32x4 acc[4] = {};

    #pragma unroll
    for (int k0 = 0; k0 < C2; k0 += 64) {
        #pragma unroll
        for (int h = 0; h < 2; h++) {
            bf16x8 af, bfr[4];
            af = *(const bf16x8*)&fsm[(wm * 16 + r) * 264 + k0 + h * 32 + q * 8];
            #pragma unroll
            for (int j = 0; j < 4; j++)
                bfr[j] = *(const bf16x8*)(Bt +
                    (size_t)(wn * 64 + j * 16 + r) * C2 + k0 + h * 32 + q * 8);
            #pragma unroll
            for (int j = 0; j < 4; j++)
                acc[j] = __builtin_amdgcn_mfma_f32_16x16x32_bf16(
                    af, bfr[j], acc[j], 0, 0, 0);
        }
    }
    __syncthreads();   // all feat reads done -> safe to alias STF onto fsm

    // epilogue: stage fp32 tile in aliased LDS, then full-line float4 flush
    float* STF = (float*)fsm;              // [32][132]
    #pragma unroll
    for (int j = 0; j < 4; j++) {
        const int ch = wn * 64 + j * 16 + r;
        const float bo = bias[ch];
        const int mb = wm * 16 + q * 4;
        #pragma unroll
        for (int p = 0; p < 4; p++)
            STF[(mb + p) * 132 + ch] = acc[j][p] + bo;
    }
    __syncthreads();
    #pragma unroll
    for (int i = 0; i < 4; i++) {          // 32x128 fp32 = 1024 float4
        int idx = tid + i * 256;
        int row = idx >> 5, c4 = (idx & 31) * 4;
        if (m0 + row < N)
            *(float4*)(Cf + (size_t)(m0 + row) * C_OUT + c4) =
                *(const float4*)&STF[row * 132 + c4];
    }
}

extern "C" void kernel_launch(void* const* d_in, const int* in_sizes, int n_in,
                              void* d_out, int out_size, void* d_ws, size_t ws_size,
                              hipStream_t stream)
{
    const float* features = (const float*)d_in[0];
    const int*   nidx     = (const int*)d_in[1];
    const float* W1       = (const float*)d_in[2];
    const float* b1       = (const float*)d_in[3];
    const float* gamma    = (const float*)d_in[4];
    const float* beta     = (const float*)d_in[5];
    const float* mean     = (const float*)d_in[6];
    const float* var      = (const float*)d_in[7];
    const float* Ws       = (const float*)d_in[8];
    const float* Wm       = (const float*)d_in[9];
    const float* bm       = (const float*)d_in[10];
    float* out = (float*)d_out;

    const int N = in_sizes[0] / C_IN;   // 50000

    u16* packed = (u16*)d_ws;                      // N x 512 interleaved pairs
    u16* W1t    = packed + (size_t)N * 512;        // 256 x 128
    u16* Wst    = W1t + 256 * 128;                 // 256 x 256
    u16* Wmt    = Wst + 256 * 256;                 // 128 x 256
    float4* bnp = (float4*)(Wmt + 128 * 256);      // 256 folded BN params

    prep_k<<<dim3(256, 4), 256, 0, stream>>>(W1, Ws, Wm, b1, gamma, beta,
                                             mean, var, W1t, Wst, Wmt, bnp);

    const int MT = (N + 63) / 64;        // 782
    const int GT = (N + PTS - 1) / PTS;  // 1563

    mlp_k<<<MT, 256, 0, stream>>>(features, W1t, Wst, bnp, packed, N);
    gather_out_k<<<GT, 256, 0, stream>>>(packed, nidx, Wmt, bm, out, N);
}

// Round 5
// 241.520 us; speedup vs baseline: 2.0368x; 1.2607x over previous
//
#include <hip/hip_runtime.h>
#include <cstddef>

// Problem shape (fixed): N=50000, K=16, C_IN=128, C2=256, C_OUT=128.
#define C_IN  128
#define C2    256
#define C_OUT 128
#define KNBR  16
#define PTS   32     // points per gather_out block

typedef unsigned short u16;
typedef __attribute__((ext_vector_type(8))) short bf16x8;   // 8 bf16 (4 VGPRs)
typedef __attribute__((ext_vector_type(8))) unsigned short u16x8; // 16B payload
typedef __attribute__((ext_vector_type(4))) float f32x4;

__device__ __forceinline__ float bf2f(u16 h) {
    return __uint_as_float(((unsigned int)h) << 16);
}
__device__ __forceinline__ u16 f2bf(float x) {
    unsigned int u = __float_as_uint(x);
    return (u16)((u + 0x7fffu + ((u >> 16) & 1u)) >> 16);
}

// Transpose + convert weights to bf16, n-major [N][K]; fold BN params.
__global__ void prep_k(const float* __restrict__ W1, const float* __restrict__ Ws,
                       const float* __restrict__ Wm, const float* __restrict__ b1,
                       const float* __restrict__ gamma, const float* __restrict__ beta,
                       const float* __restrict__ mean, const float* __restrict__ var,
                       u16* __restrict__ W1t, u16* __restrict__ Wst,
                       u16* __restrict__ Wmt, float4* __restrict__ bnp)
{
    const int n = blockIdx.x, t = threadIdx.x;
    if (blockIdx.y == 0) {
        if (t < 128) W1t[n * 128 + t] = f2bf(W1[t * 256 + n]);
    } else if (blockIdx.y == 1) {
        Wst[n * 256 + t] = f2bf(Ws[t * 256 + n]);
    } else if (blockIdx.y == 2) {
        if (n < 128) Wmt[n * 256 + t] = f2bf(Wm[t * 128 + n]);
    } else if (n == 0) {
        // x = (relu(z+b1)-mu)*iv + be = relu(z+c1)*c2 + c3
        float iv = gamma[t] * rsqrtf(var[t] + 1e-5f);
        bnp[t] = make_float4(b1[t], iv, beta[t] - mean[t] * iv, 0.f);
    }
}

// ---------------------------------------------------------------------------
// LESSONS ENCODED:
//  R7:  accumulator arrays indexed by non-unrolled loop vars spill to scratch.
//  R9:  scattered sub-dword global stores -> write-allocate RMW (16x bytes).
//  R10: 1-block/CU weight-stationary waves have zero latency hiding.
//  R11: packed row CHANNEL-INTERLEAVED [ey0,x0,ey1,x1,...]: one dwordx4/lane
//       per neighbor row; e,x same lane for the FMA.
//  R12: gather random-read fabric pins at ~3.4-3.7 TB/s; FETCH ~370 MB is
//       structural. Per-wave MLP variations (4/8/16 in flight) all land
//       110-123 us -> leave gather alone, it is at its ceiling.
//  R14: launch_bounds cap below per-PHASE live state => silent scratch spill.
//       R4's wave-private mlp (cap 168, acc2+xa+pipeline > cap) regressed
//       ~50 us. Audit live VGPRs per phase; when in doubt, NO min-wave cap.
//  R15 (this round): restore R2's barrier-tiled mlp (VGPR-safe acc[2][4])
//       and exploit the acc-layout identity: GEMM2's ey(row,col) lane ==
//       GEMM1's x(row,col) lane -> keep x in 32 VGPRs (bf16), store
//       (ey|x<<16) dword lane-locally. Deletes the ey LDS staging + both
//       flush passes (4+ barriers, 2 LDS round-trips per tile).
// packed row (512 u16): 256 pairs of (ey[c], x[c]), both bf16.
// ---------------------------------------------------------------------------

// Fused MLP, 64-row blocks (69.6 KB LDS -> 2 blocks/CU), 4 waves (2M x 2N):
//   GEMM1: x = BN(relu(F @ W1 + b1)) -> xs (LDS, for GEMM2-A) + xr (VGPR)
//   GEMM2: ey = exp(x @ Ws) -> lane-local interleaved (ey|x) dword stores
__global__ __launch_bounds__(256)
void mlp_k(const float* __restrict__ F, const u16* __restrict__ W1t,
           const u16* __restrict__ Wst, const float4* __restrict__ bnp,
           u16* __restrict__ packed, int N)
{
    __shared__ u16 As[64][136];    // features tile (GEMM1 A)
    __shared__ u16 Bs[128][72];    // weight k-slice staging
    __shared__ u16 xs[64][264];    // x tile, full K=256 (GEMM2 A source)

    const int tid = threadIdx.x;
    const int w = tid >> 6, l = tid & 63, q = l >> 4, r = l & 15;
    const int wm = w & 1, wn = w >> 1;
    const int m0 = blockIdx.x * 64;

    // stage As: 64 x 128 fp32 -> bf16 (2048 float4, 8/thread)
    #pragma unroll
    for (int i = 0; i < 8; i++) {
        int idx = tid + i * 256;
        int row = idx >> 5, c4 = (idx & 31) * 4;
        int gm = m0 + row;
        float4 v = make_float4(0.f, 0.f, 0.f, 0.f);
        if (gm < N) v = *(const float4*)(F + (size_t)gm * C_IN + c4);
        ushort4 h;
        h.x = f2bf(v.x); h.y = f2bf(v.y); h.z = f2bf(v.z); h.w = f2bf(v.w);
        *(ushort4*)&As[row][c4] = h;
    }

    // x kept in registers, bf16-packed: [nh][i][j] ushort4 (p in lanes of u64)
    ushort4 xr[2][2][4];

    // ---- GEMM1: x = F @ W1, two 128-col halves (nh fully unrolled) ----
    #pragma unroll
    for (int nh = 0; nh < 2; nh++) {
        f32x4 acc[2][4] = {};
        #pragma unroll 1
        for (int k0 = 0; k0 < C_IN; k0 += 64) {
            __syncthreads();   // prior Bs readers done (also covers As stage)
            #pragma unroll
            for (int i = 0; i < 4; i++) {
                int idx = tid + i * 256;
                int row = idx >> 3, g = (idx & 7) * 8;
                *(uint4*)&Bs[row][g] = *(const uint4*)(
                    W1t + (size_t)(nh * 128 + row) * C_IN + k0 + g);
            }
            __syncthreads();
            #pragma unroll
            for (int h = 0; h < 2; h++) {
                bf16x8 af[2], bfr[4];
                #pragma unroll
                for (int i = 0; i < 2; i++)
                    af[i] = *(const bf16x8*)&As[wm * 32 + i * 16 + r][k0 + h * 32 + q * 8];
                #pragma unroll
                for (int j = 0; j < 4; j++)
                    bfr[j] = *(const bf16x8*)&Bs[wn * 64 + j * 16 + r][h * 32 + q * 8];
                #pragma unroll
                for (int i = 0; i < 2; i++)
                    #pragma unroll
                    for (int j = 0; j < 4; j++)
                        acc[i][j] = __builtin_amdgcn_mfma_f32_16x16x32_bf16(
                            af[i], bfr[j], acc[i][j], 0, 0, 0);
            }
        }
        // epilogue 1: x = relu(z+c1)*c2+c3 -> xs (LDS) AND xr (VGPR, bf16)
        #pragma unroll
        for (int j = 0; j < 4; j++) {
            const int ch = nh * 128 + wn * 64 + j * 16 + r;
            const float4 bp = bnp[ch];
            #pragma unroll
            for (int i = 0; i < 2; i++) {
                const int mb = wm * 32 + i * 16 + q * 4;
                ushort4 hx;
                #pragma unroll
                for (int p = 0; p < 4; p++) {
                    float x = fmaxf(acc[i][j][p] + bp.x, 0.f) * bp.y + bp.z;
                    u16 h = f2bf(x);
                    xs[mb + p][ch] = h;
                    if (p == 0) hx.x = h; else if (p == 1) hx.y = h;
                    else if (p == 2) hx.z = h; else hx.w = h;
                }
                xr[nh][i][j] = hx;
            }
        }
    }

    // ---- GEMM2: ey = exp(x @ Ws); A from xs; direct lane-local epilogue ----
    #pragma unroll
    for (int nh = 0; nh < 2; nh++) {
        f32x4 acc[2][4] = {};
        #pragma unroll 1
        for (int k0 = 0; k0 < C2; k0 += 64) {
            __syncthreads();   // prior Bs readers done; 1st iter: xs complete
            #pragma unroll
            for (int i = 0; i < 4; i++) {
                int idx = tid + i * 256;
                int row = idx >> 3, g = (idx & 7) * 8;
                *(uint4*)&Bs[row][g] = *(const uint4*)(
                    Wst + (size_t)(nh * 128 + row) * C2 + k0 + g);
            }
            __syncthreads();
            #pragma unroll
            for (int h = 0; h < 2; h++) {
                bf16x8 af[2], bfr[4];
                #pragma unroll
                for (int i = 0; i < 2; i++)
                    af[i] = *(const bf16x8*)&xs[wm * 32 + i * 16 + r][k0 + h * 32 + q * 8];
                #pragma unroll
                for (int j = 0; j < 4; j++)
                    bfr[j] = *(const bf16x8*)&Bs[wn * 64 + j * 16 + r][h * 32 + q * 8];
                #pragma unroll
                for (int i = 0; i < 2; i++)
                    #pragma unroll
                    for (int j = 0; j < 4; j++)
                        acc[i][j] = __builtin_amdgcn_mfma_f32_16x16x32_bf16(
                            af[i], bfr[j], acc[i][j], 0, 0, 0);
            }
        }
        // epilogue 2: ey=exp(acc); pair with register-held x (same lane,
        // same (row,ch) by layout identity); u32 store: 16 consecutive u32
        // per (q-row) -> 4 x 64B segments per instruction. No LDS, no barrier.
        #pragma unroll
        for (int j = 0; j < 4; j++) {
            const int ch = nh * 128 + wn * 64 + j * 16 + r;
            #pragma unroll
            for (int i = 0; i < 2; i++) {
                const int mb = wm * 32 + i * 16 + q * 4;
                const ushort4 hx = xr[nh][i][j];
                #pragma unroll
                for (int p = 0; p < 4; p++) {
                    const int gm = m0 + mb + p;
                    if (gm < N) {
                        unsigned xv = (p == 0) ? hx.x : (p == 1) ? hx.y
                                    : (p == 2) ? hx.z : hx.w;
                        unsigned ey = f2bf(__expf(acc[i][j][p]));
                        *(unsigned*)(packed + (size_t)gm * 512 + ch * 2) =
                            ey | (xv << 16);
                    }
                }
            }
        }
    }
}

// Fused gather + attentive pool + output GEMM. 32 points/block, 4 waves.
// Phase 1: each wave pools 8 points; 16 rows gathered in TWO passes of 8
//          (32-VGPR payload, fits under the (256,5) cap -> no scratch).
// Phase 2: out[32 x 128] = feat @ Wmt + bm, B direct from L2-resident Wmt;
//          fp32 epilogue staging ALIASES the feat buffer.
// LDS: 2KB rows + 16.9KB feat/STF = 18.9KB; VGPR cap 102 -> 5 blocks/CU.
__global__ __launch_bounds__(256, 5)
void gather_out_k(const u16* __restrict__ packed, const int* __restrict__ nidx,
                  const u16* __restrict__ Bt, const float* __restrict__ bias,
                  float* __restrict__ Cf, int N)
{
    __shared__ int rows[PTS * KNBR];                 // 2 KB
    __shared__ __align__(16) u16 fsm[PTS * 264];     // feat bf16 / STF fp32 alias

    const int tid = threadIdx.x;
    const int w = tid >> 6, l = tid & 63, q = l >> 4, r = l & 15;
    const int m0 = blockIdx.x * PTS;

    // stage neighbor indices: PTS*16 = 512 ints, 2/thread
    #pragma unroll
    for (int i = 0; i < 2; i++) {
        int idx = tid + i * 256;
        int n = m0 + (idx >> 4);
        rows[idx] = (n < N) ? nidx[n * KNBR + (idx & 15)] : 0;
    }
    __syncthreads();

    // ---- phase 1: gather + pool, wave w -> points w*8 .. w*8+7 ----
    #pragma unroll 1
    for (int ip = 0; ip < 8; ip++) {
        const int pl = w * 8 + ip;
        float num[4] = {0.f, 0.f, 0.f, 0.f};
        float den[4] = {0.f, 0.f, 0.f, 0.f};
        #pragma unroll 1
        for (int hf = 0; hf < 2; hf++) {
            u16x8 v[8];
            #pragma unroll
            for (int k = 0; k < 8; k++)
                v[k] = *(const u16x8*)(packed +
                    (size_t)rows[pl * KNBR + hf * 8 + k] * 512 + l * 8);
            #pragma unroll
            for (int k = 0; k < 8; k++) {
                #pragma unroll
                for (int c = 0; c < 4; c++) {
                    float e = bf2f((u16)v[k][2 * c]);
                    float x = bf2f((u16)v[k][2 * c + 1]);
                    den[c] += e;
                    num[c] = fmaf(e, x, num[c]);
                }
            }
        }
        ushort4 o;
        o.x = f2bf(num[0] / den[0]); o.y = f2bf(num[1] / den[1]);
        o.z = f2bf(num[2] / den[2]); o.w = f2bf(num[3] / den[3]);
        *(ushort4*)&fsm[pl * 264 + l * 4] = o;   // rows >= N: garbage, never stored
    }
    __syncthreads();   // feat tile complete

    // ---- phase 2: out GEMM, wave grid 2M x 2N; B direct from L2 ----
    const int wm = w & 1, wn = w >> 1;
    f32x4 acc[4] = {};

    #pragma unroll
    for (int k0 = 0; k0 < C2; k0 += 64) {
        #pragma unroll
        for (int h = 0; h < 2; h++) {
            bf16x8 af, bfr[4];
            af = *(const bf16x8*)&fsm[(wm * 16 + r) * 264 + k0 + h * 32 + q * 8];
            #pragma unroll
            for (int j = 0; j < 4; j++)
                bfr[j] = *(const bf16x8*)(Bt +
                    (size_t)(wn * 64 + j * 16 + r) * C2 + k0 + h * 32 + q * 8);
            #pragma unroll
            for (int j = 0; j < 4; j++)
                acc[j] = __builtin_amdgcn_mfma_f32_16x16x32_bf16(
                    af, bfr[j], acc[j], 0, 0, 0);
        }
    }
    __syncthreads();   // all feat reads done -> safe to alias STF onto fsm

    // epilogue: stage fp32 tile in aliased LDS, then full-line float4 flush
    float* STF = (float*)fsm;              // [32][132]
    #pragma unroll
    for (int j = 0; j < 4; j++) {
        const int ch = wn * 64 + j * 16 + r;
        const float bo = bias[ch];
        const int mb = wm * 16 + q * 4;
        #pragma unroll
        for (int p = 0; p < 4; p++)
            STF[(mb + p) * 132 + ch] = acc[j][p] + bo;
    }
    __syncthreads();
    #pragma unroll
    for (int i = 0; i < 4; i++) {          // 32x128 fp32 = 1024 float4
        int idx = tid + i * 256;
        int row = idx >> 5, c4 = (idx & 31) * 4;
        if (m0 + row < N)
            *(float4*)(Cf + (size_t)(m0 + row) * C_OUT + c4) =
                *(const float4*)&STF[row * 132 + c4];
    }
}

extern "C" void kernel_launch(void* const* d_in, const int* in_sizes, int n_in,
                              void* d_out, int out_size, void* d_ws, size_t ws_size,
                              hipStream_t stream)
{
    const float* features = (const float*)d_in[0];
    const int*   nidx     = (const int*)d_in[1];
    const float* W1       = (const float*)d_in[2];
    const float* b1       = (const float*)d_in[3];
    const float* gamma    = (const float*)d_in[4];
    const float* beta     = (const float*)d_in[5];
    const float* mean     = (const float*)d_in[6];
    const float* var      = (const float*)d_in[7];
    const float* Ws       = (const float*)d_in[8];
    const float* Wm       = (const float*)d_in[9];
    const float* bm       = (const float*)d_in[10];
    float* out = (float*)d_out;

    const int N = in_sizes[0] / C_IN;   // 50000

    u16* packed = (u16*)d_ws;                      // N x 512 interleaved pairs
    u16* W1t    = packed + (size_t)N * 512;        // 256 x 128
    u16* Wst    = W1t + 256 * 128;                 // 256 x 256
    u16* Wmt    = Wst + 256 * 256;                 // 128 x 256
    float4* bnp = (float4*)(Wmt + 128 * 256);      // 256 folded BN params

    prep_k<<<dim3(256, 4), 256, 0, stream>>>(W1, Ws, Wm, b1, gamma, beta,
                                             mean, var, W1t, Wst, Wmt, bnp);

    const int MT = (N + 63) / 64;        // 782
    const int GT = (N + PTS - 1) / PTS;  // 1563

    mlp_k<<<MT, 256, 0, stream>>>(features, W1t, Wst, bnp, packed, N);
    gather_out_k<<<GT, 256, 0, stream>>>(packed, nidx, Wmt, bm, out, N);
}